// Round 8
// baseline (734.041 us; speedup 1.0000x reference)
//
#include <hip/hip_runtime.h>
#include <stdint.h>
#include <stddef.h>

// CNNLSTM: embed -> conv1d(K=5) -> ReLU -> maxpool4 -> LSTM(T=1023,H=128) -> fc(2)
// Inputs: x int32; all float tensors float32. Output f32.
// Internals: bf16 MFMA for conv + input-projection GEMMs; f16 dot2 recurrence.

typedef __bf16 bf16;
typedef __bf16 bf16x8 __attribute__((ext_vector_type(8)));
typedef float  f32x4  __attribute__((ext_vector_type(4)));
typedef _Float16 f16;
typedef f16 f16x2 __attribute__((ext_vector_type(2)));
typedef f16 f16x4 __attribute__((ext_vector_type(4)));
typedef f16 f16x8 __attribute__((ext_vector_type(8)));

#define MFMA16(a, b, c) __builtin_amdgcn_mfma_f32_16x16x32_bf16((a), (b), (c), 0, 0, 0)

#if __has_builtin(__builtin_amdgcn_fdot2)
#define DOT2(a, b, c) __builtin_amdgcn_fdot2((a), (b), (c), false)
#else
#define DOT2(a, b, c) ((c) + (float)(a).x * (float)(b).x + (float)(a).y * (float)(b).y)
#endif

// Barrier draining LDS (lgkm) but NOT in-flight global prefetch loads.
#define LGKM_BARRIER() asm volatile("s_waitcnt lgkmcnt(0)\ns_barrier" ::: "memory")

// DPP quad_perm helpers (VALU pipe -- no LDS/shuffle traffic).
// ctrl must be an immediate -> template parameter.
// xor1 = perm{1,0,3,2} = 0xB1 ; xor2 = perm{2,3,0,1} = 0x4E
template <int CTRL>
__device__ inline float qbcast(float v) {
    int s = __builtin_bit_cast(int, v);
    int d = __builtin_amdgcn_update_dpp(0, s, CTRL, 0xF, 0xF, true);
    return __builtin_bit_cast(float, d);
}
__device__ inline float qreduce(float a) {       // sum over the 4 quad lanes
    a += qbcast<0xB1>(a);
    a += qbcast<0x4E>(a);
    return a;
}

// ---------------- ws layout (bytes) ----------------
#define WS_BT     0               // conv weights repacked [64][640] bf16 =    81,920
#define WS_WIHB   81920           // w_ih bf16 [512][64]                  =    65,536
#define WS_POOLED 278528          // pooled bf16 [64][1024][64]           = 8,388,608
#define WS_EMB    8667136         // emb bf16 [20000][128]                = 5,120,000
#define WS_XG     8667136         // xgc f16 [64][128][128][4][8]         = 67,108,864
// (xgc overlaps emb_bf16: emb dead after conv_pool)

// ============ prep A: emb f32 -> bf16 ============
__global__ void emb_cvt_k(const float* __restrict__ emb, bf16* __restrict__ embb) {
    int g = blockIdx.x * 256 + threadIdx.x;
    f32x4 v = *(const f32x4*)(emb + g * 4);
    bf16* d = embb + g * 4;
    d[0] = (bf16)v[0]; d[1] = (bf16)v[1]; d[2] = (bf16)v[2]; d[3] = (bf16)v[3];
}

// ============ prep B: conv_w repack->bf16; w_ih->bf16 ============
__global__ void prep_small_k(const float* __restrict__ conv_w, bf16* __restrict__ bt,
                             const float* __restrict__ w_ih, bf16* __restrict__ w_ihb) {
    int g = blockIdx.x * 256 + threadIdx.x;
    if (g < 64 * 640) {
        int f = g / 640, kk = g - f * 640;
        int k = kk >> 7, e = kk & 127;
        bt[g] = (bf16)conv_w[(f * 128 + e) * 5 + k];
    } else {
        int h = g - 64 * 640;
        if (h < 512 * 64) w_ihb[h] = (bf16)w_ih[h];
    }
}

// ============ kernel 1: embed-gather + conv + ReLU + pool4 ============
__global__ __launch_bounds__(256, 2) void conv_pool_k(
    const int* __restrict__ x, const bf16* __restrict__ embb,
    const bf16* __restrict__ bt, const float* __restrict__ conv_b,
    bf16* __restrict__ pooled)
{
    __shared__ bf16 T[144 * 136];  // 136 = 128 + 8 pad
    const int b   = blockIdx.x >> 5;
    const int l0  = (blockIdx.x & 31) << 7;
    const int tid = threadIdx.x;
    const int ln  = tid & 63, w = tid >> 6;
    const int l15 = ln & 15, quad = ln >> 4;
    const int f   = w * 16 + l15;

    bf16x8 bfrag[20];
    #pragma unroll
    for (int kc = 0; kc < 20; ++kc) {
        uint4 v = *(const uint4*)(bt + f * 640 + kc * 32 + quad * 8);
        bfrag[kc] = __builtin_bit_cast(bf16x8, v);
    }
    const float cb = conv_b[f];

    #pragma unroll
    for (int p = 0; p < 9; ++p) {
        int r = p * 16 + (tid >> 4);
        int cg = tid & 15;
        int token = l0 + r; if (token > 4095) token = 4095;
        int idx = x[b * 4096 + token];
        uint4 v = *(const uint4*)(embb + idx * 128 + cg * 8);
        *(uint4*)(&T[r * 136 + cg * 8]) = v;
    }
    __syncthreads();

    f32x4 acc[8];
    #pragma unroll
    for (int tm = 0; tm < 8; ++tm) acc[tm] = (f32x4){0.f, 0.f, 0.f, 0.f};

    #pragma unroll
    for (int kc = 0; kc < 20; ++kc) {
        const int ktap = kc >> 2;
        const int ecol = (kc & 3) * 32 + quad * 8;
        #pragma unroll
        for (int tm = 0; tm < 8; ++tm) {
            int row = tm * 16 + l15 + ktap;
            bf16x8 a = *(const bf16x8*)(&T[row * 136 + ecol]);
            acc[tm] = MFMA16(a, bfrag[kc], acc[tm]);
        }
    }

    #pragma unroll
    for (int tm = 0; tm < 8; ++tm) {
        float mx = fmaxf(fmaxf(acc[tm][0], acc[tm][1]), fmaxf(acc[tm][2], acc[tm][3]));
        mx = fmaxf(mx + cb, 0.f);
        int t = (l0 >> 2) + tm * 4 + quad;
        if (t < 1023) pooled[(b * 1024 + t) * 64 + f] = (bf16)mx;
    }
}

// ============ kernel 2: xgc = pooled @ w_ih^T + (b_ih+b_hh), chunk-layout f16 ============
// xgc[b][c][unit][gate][j], t = c*8+j.
__global__ __launch_bounds__(256, 2) void xg_gemm_k(
    const bf16* __restrict__ pooled, const bf16* __restrict__ w_ihb,
    const float* __restrict__ b_ih, const float* __restrict__ b_hh,
    f16* __restrict__ xg)
{
    __shared__ bf16 A[256 * 72];  // 72 = 64 + 8 pad
    const int m0  = blockIdx.x * 256;
    const int tid = threadIdx.x;
    const int ln  = tid & 63, w = tid >> 6;
    const int l15 = ln & 15, quad = ln >> 4;

    #pragma unroll
    for (int i = 0; i < 8; ++i) {
        int task = i * 256 + tid;
        int row = task >> 3, ch = task & 7;
        uint4 v = *(const uint4*)(pooled + (m0 + row) * 64 + ch * 8);
        *(uint4*)(&A[row * 72 + ch * 8]) = v;
    }
    __syncthreads();

    bf16x8 afrag[4][2];
    #pragma unroll
    for (int mt = 0; mt < 4; ++mt)
        #pragma unroll
        for (int kc = 0; kc < 2; ++kc)
            afrag[mt][kc] = *(const bf16x8*)(&A[((w * 4 + mt) * 16 + l15) * 72 + kc * 32 + quad * 8]);

    const int b_idx = m0 >> 10;
    const int tbase = m0 & 1023;

    for (int nt = 0; nt < 32; ++nt) {
        const int nn = nt * 16 + l15;
        uint4 v0 = *(const uint4*)(w_ihb + nn * 64 + quad * 8);
        uint4 v1 = *(const uint4*)(w_ihb + nn * 64 + 32 + quad * 8);
        bf16x8 bf0 = __builtin_bit_cast(bf16x8, v0);
        bf16x8 bf1 = __builtin_bit_cast(bf16x8, v1);
        const float bias = b_ih[nn] + b_hh[nn];
        const int unit = nn & 127, gate = nn >> 7;
        #pragma unroll
        for (int mt = 0; mt < 4; ++mt) {
            f32x4 acc = (f32x4){0.f, 0.f, 0.f, 0.f};
            acc = MFMA16(afrag[mt][0], bf0, acc);
            acc = MFMA16(afrag[mt][1], bf1, acc);
            int t0 = tbase + (w * 4 + mt) * 16 + quad * 4;   // t0 % 4 == 0
            f16x4 sv = {(f16)(acc[0] + bias), (f16)(acc[1] + bias),
                        (f16)(acc[2] + bias), (f16)(acc[3] + bias)};
            size_t off = (((size_t)(b_idx * 128 + (t0 >> 3)) * 128 + unit) * 4 + gate) * 8 + (t0 & 7);
            *(f16x4*)(xg + off) = sv;   // 8B store, (t0&7) in {0,4}
        }
    }
}

// ============ kernel 3: LSTM recurrence + fc head ============
// 64 WGs x 512 threads (8 waves, 2/EU). Quad (4 lanes) owns unit u = t>>2;
// lane kq = t&3 holds ALL 4 gate rows over K-window [32kq, 32kq+32):
// 128 f16 = 64 weight VGPRs -> total live ~95 regs, fits the 128 budget the
// allocator insists on (R4-R6: 256-thread variants need 128 weight regs alone
// -> unavoidable spill/remat; that was the ~800 cy/step mystery).
// Quad reduction + x broadcast via DPP quad_perm (VALU pipe, no LDS, no
// extra barrier). Lane kq==0 does activations + cell + ds_write_b16.
__device__ inline float sigm_(float v) {
    v = fminf(fmaxf(v, -30.f), 30.f);
    return __builtin_amdgcn_rcpf(1.f + __expf(-v));
}
__device__ inline float tanh_(float v) {
    v = fminf(fmaxf(v, -15.f), 15.f);
    return 1.f - 2.f * __builtin_amdgcn_rcpf(__expf(2.f * v) + 1.f);
}

__global__ __launch_bounds__(512, 2) void lstm_fc_k(
    const f16* __restrict__ xgc, const float* __restrict__ w_hh,
    const float* __restrict__ fc_w, const float* __restrict__ fc_b,
    float* __restrict__ out)
{
    __shared__ __align__(16) f16 hp[2][128];
    const int b  = blockIdx.x;
    const int t  = threadIdx.x;   // 0..511
    const int u  = t >> 2;        // unit 0..127
    const int kq = t & 3;         // K-quarter

    // 4 gates x 32 K = 128 f16 = 64 f16x2 VGPRs
    f16x2 wv[4][16];
    #pragma unroll
    for (int g = 0; g < 4; ++g) {
        const float* wr = w_hh + (g * 128 + u) * 128 + kq * 32;
        #pragma unroll
        for (int c = 0; c < 8; ++c) {
            f32x4 v = *(const f32x4*)(wr + c * 4);
            wv[g][c * 2 + 0] = (f16x2){(f16)v[0], (f16)v[1]};
            wv[g][c * 2 + 1] = (f16x2){(f16)v[2], (f16)v[3]};
        }
    }

    // lane kq prefetches gate kq's x-chunk: 16B/lane, quad-contiguous
    const f16* xb = xgc + (size_t)b * 524288 + (size_t)u * 32 + kq * 8;
    f16x8 xq = *(const f16x8*)xb, nxq;

    if (t < 128) hp[0][t] = (f16)0.f;
    float cst = 0.f;
    int p = 0;
    LGKM_BARRIER();

    auto step = [&](int j) {
        const f16* hsrc = &hp[p][kq * 32];
        float a0 = 0.f, a1 = 0.f, a2 = 0.f, a3 = 0.f;
        #pragma unroll
        for (int c = 0; c < 4; ++c) {
            f16x8 h8 = *(const f16x8*)(hsrc + c * 8);   // quad-strided b128, 2-way banks (free)
            f16x2 p0 = {h8[0], h8[1]}, p1 = {h8[2], h8[3]};
            f16x2 p2 = {h8[4], h8[5]}, p3 = {h8[6], h8[7]};
            a0 = DOT2(wv[0][c*4+0], p0, a0); a0 = DOT2(wv[0][c*4+1], p1, a0);
            a0 = DOT2(wv[0][c*4+2], p2, a0); a0 = DOT2(wv[0][c*4+3], p3, a0);
            a1 = DOT2(wv[1][c*4+0], p0, a1); a1 = DOT2(wv[1][c*4+1], p1, a1);
            a1 = DOT2(wv[1][c*4+2], p2, a1); a1 = DOT2(wv[1][c*4+3], p3, a1);
            a2 = DOT2(wv[2][c*4+0], p0, a2); a2 = DOT2(wv[2][c*4+1], p1, a2);
            a2 = DOT2(wv[2][c*4+2], p2, a2); a2 = DOT2(wv[2][c*4+3], p3, a2);
            a3 = DOT2(wv[3][c*4+0], p0, a3); a3 = DOT2(wv[3][c*4+1], p1, a3);
            a3 = DOT2(wv[3][c*4+2], p2, a3); a3 = DOT2(wv[3][c*4+3], p3, a3);
        }
        // quad-reduce each gate total (identical in all 4 lanes afterwards)
        a0 = qreduce(a0); a1 = qreduce(a1); a2 = qreduce(a2); a3 = qreduce(a3);
        // broadcast x: lane g holds gate g's x -> gather into lane 0's mapping
        float xv = (float)xq[j];
        float x1 = qbcast<0xB1>(xv);          // lane0: gate1 (f)
        float x2 = qbcast<0x4E>(xv);          // lane0: gate2 (g)
        float x3 = qbcast<0x4E>(x1);          // lane0: gate3 (o)
        if (kq == 0) {
            float ig = sigm_(a0 + xv);
            float fg = sigm_(a1 + x1);
            float gg = tanh_(a2 + x2);
            float og = sigm_(a3 + x3);
            cst = fg * cst + ig * gg;
            hp[p ^ 1][u] = (f16)(og * tanh_(cst));
        }
        p ^= 1;
        LGKM_BARRIER();
    };

    for (int c = 0; c < 127; ++c) {
        nxq = *(const f16x8*)(xb + (size_t)(c + 1) * 4096);  // prefetch next chunk
        #pragma unroll
        for (int j = 0; j < 8; ++j) step(j);
        xq = nxq;
    }
    #pragma unroll
    for (int j = 0; j < 7; ++j) step(j);   // steps 1016..1022

    // fc: out[b][c] = h_T . fc_w[c] + fc_b[c]   (final h in hp[p])
    if (t < 128) {
        int c2 = t >> 6, j2 = t & 63;
        float pr = (float)hp[p][2 * j2] * fc_w[c2 * 128 + 2 * j2]
                 + (float)hp[p][2 * j2 + 1] * fc_w[c2 * 128 + 2 * j2 + 1];
        #pragma unroll
        for (int off = 32; off > 0; off >>= 1) pr += __shfl_down(pr, off, 64);
        if (j2 == 0) out[b * 2 + c2] = pr + fc_b[c2];
    }
}

// ============================ launcher ============================
extern "C" void kernel_launch(void* const* d_in, const int* in_sizes, int n_in,
                              void* d_out, int out_size, void* d_ws, size_t ws_size,
                              hipStream_t stream) {
    const int*   x      = (const int*)d_in[0];
    const float* emb    = (const float*)d_in[1];
    const float* conv_w = (const float*)d_in[2];
    const float* conv_b = (const float*)d_in[3];
    const float* w_ih   = (const float*)d_in[4];
    const float* w_hh   = (const float*)d_in[5];
    const float* b_ih   = (const float*)d_in[6];
    const float* b_hh   = (const float*)d_in[7];
    const float* fc_w   = (const float*)d_in[8];
    const float* fc_b   = (const float*)d_in[9];
    float* out = (float*)d_out;

    char* ws = (char*)d_ws;
    bf16* bt     = (bf16*)(ws + WS_BT);
    bf16* w_ihb  = (bf16*)(ws + WS_WIHB);
    bf16* pooled = (bf16*)(ws + WS_POOLED);
    bf16* embb   = (bf16*)(ws + WS_EMB);
    f16*  xg     = (f16*)(ws + WS_XG);   // overlaps embb (emb dead after conv_pool)

    emb_cvt_k<<<2500, 256, 0, stream>>>(emb, embb);
    prep_small_k<<<288, 256, 0, stream>>>(conv_w, bt, w_ih, w_ihb);
    conv_pool_k<<<2048, 256, 0, stream>>>(x, embb, bt, conv_b, pooled);
    xg_gemm_k<<<256, 256, 0, stream>>>(pooled, w_ihb, b_ih, b_hh, xg);
    lstm_fc_k<<<64, 512, 0, stream>>>(xg, w_hh, fc_w, fc_b, out);
}